// Round 13
// baseline (320.564 us; speedup 1.0000x reference)
//
#include <hip/hip_runtime.h>

// GatedMoE on MI355X (gfx950), fp16 MFMA path, round 17.
// vs r16 (315.4, best): rebalance prep + strip gemm1 to pure GEMM.
// Launch1 = router + cvt-W1[e0..3] (router latency overlaps cvt BW).
// Launch2 = scan (hidden, r16 win) + cvt-W1[e4..7] + cvt-W2.
// gemm1 loses its appended cvt-W2 tail (worth ~12us, r9 measurement) ->
// 1280 blocks, the measured-75us r4 form. Same total prep bytes, evenly
// split across the two serial BW-bound launches. gemm2/gather = r12.

typedef _Float16 half8 __attribute__((ext_vector_type(8)));
typedef _Float16 half4t __attribute__((ext_vector_type(4)));
typedef float f4 __attribute__((ext_vector_type(4)));

#define N_TOK 4096
#define DDIM  768
#define HDIM  2048
#define NEXP  8
#define CAP   614   // int(1.2 * 4096 / 8)
#define CAPP  640

// ---- workspace layout (bytes) ----
#define XH_OFF    0L           // (4097*768) fp16
#define W1T_OFF   6292992L     // [8][4096][768] fp16 (dead after gemm1)
#define YB_OFF    6292992L     // [16][640][768] fp32 ybuf (gemm2->gather), aliases w1t
#define W2T_OFF   56624640L    // [8][768][2048] fp16
#define ACT_OFF   81790464L    // [16][640][2048] fp16
#define EIDX_OFF  123733504L   // [4096][2] int
#define WTS_OFF   123766272L   // [4096][2] float
#define TOKL_OFF  123799040L   // [16][640] int
#define CNT_OFF   123840000L   // [16] int
#define INV_OFF   123840256L   // [4096][2] int (tok,k) -> z*CAPP+slot | -1

__device__ __forceinline__ void gld16(const void* g, void* l) {
  __builtin_amdgcn_global_load_lds(
      (const __attribute__((address_space(1))) unsigned int*)g,
      (__attribute__((address_space(3))) unsigned int*)l, 16, 0, 0);
}

// -------------------- wide transpose+convert: 64 rows x 128 cols --------------------
__device__ __forceinline__ void cvt2_tile(const float* __restrict__ src,
                                          _Float16* __restrict__ dst,
                                          int R, int C, int e, int r0, int c0,
                                          float* __restrict__ tile) {
  long sb = (long)e * R * C;
  int t = threadIdx.x;
  int rrow = t >> 4, c4 = (t & 15) * 4;
#pragma unroll
  for (int h = 0; h < 2; h++)
#pragma unroll
    for (int i = 0; i < 4; i++) {
      int row = i * 16 + rrow;
      f4 v = *(const f4*)(src + sb + (long)(r0 + row) * C + c0 + h * 64 + c4);
      *(f4*)(&tile[h * 4416 + row * 69 + c4]) = v;
    }
  __syncthreads();
#pragma unroll
  for (int h = 0; h < 2; h++)
#pragma unroll
    for (int s = 0; s < 2; s++) {
      int idx = t + s * 256;
      int c = idx >> 3, ch = idx & 7;
      half8 hv;
#pragma unroll
      for (int j = 0; j < 8; j++) hv[j] = (_Float16)tile[h * 4416 + (ch * 8 + j) * 69 + c];
      *(half8*)(dst + sb + (long)(c0 + h * 64 + c) * R + r0 + ch * 8) = hv;
    }
}

// W1 cvt block index b2 in [0,3072): e = b2/384, 12 r-tiles x 32 col2-tiles
__device__ __forceinline__ void cvt_w1_block(const float* __restrict__ W1,
                                             _Float16* __restrict__ w1t,
                                             int b2, float* __restrict__ smem) {
  int e = b2 / 384, rem = b2 % 384;
  int cx = rem % 12, cy = rem / 12;
  cvt2_tile(W1, w1t, 768, 4096, e, cx * 64, cy * 128, smem);
}

// -------------------- launch 1: router (+x->fp16) | cvt-W1 experts 0..3 --------------------
__global__ __launch_bounds__(256) void routerCvt_kernel(const float* __restrict__ x,
                                                        const float* __restrict__ Wg,
                                                        const float* __restrict__ W1,
                                                        _Float16* __restrict__ xh,
                                                        _Float16* __restrict__ w1t,
                                                        int* __restrict__ eidx,
                                                        float* __restrict__ wts) {
  __shared__ float smem[2 * 4416];   // 35.3 KB: cvt tiles; router uses 24 KB as wgT
  int b = blockIdx.x;

  if (b >= 1025) {                   // ---- cvt W1, experts 0..3 (b2 in [0,1536))
    cvt_w1_block(W1, w1t, b - 1025, smem);
    return;
  }

  // ---- router (block-uniform path)
  int t = threadIdx.x;
  for (int i = t; i < DDIM * NEXP; i += 256) smem[(i & 7) * DDIM + (i >> 3)] = Wg[i];
  __syncthreads();
  int w = t >> 6, lane = t & 63;
  int tok = b * 4 + w;
  if (tok > N_TOK) return;
  if (tok == N_TOK) {                // zero pad row
    half4t zz; zz[0] = zz[1] = zz[2] = zz[3] = (_Float16)0.f;
#pragma unroll
    for (int j = 0; j < 3; j++) *(half4t*)(xh + (long)N_TOK * DDIM + (lane + j * 64) * 4) = zz;
    return;
  }
  const float* xr = x + (long)tok * DDIM;
#pragma unroll
  for (int j = 0; j < 3; j++) {
    f4 v = *(const f4*)(xr + (lane + j * 64) * 4);
    half4t hv;
    hv[0] = (_Float16)v[0]; hv[1] = (_Float16)v[1];
    hv[2] = (_Float16)v[2]; hv[3] = (_Float16)v[3];
    *(half4t*)(xh + (long)tok * DDIM + (lane + j * 64) * 4) = hv;
  }
  float acc[8] = {0.f, 0.f, 0.f, 0.f, 0.f, 0.f, 0.f, 0.f};
#pragma unroll
  for (int i = 0; i < 12; i++) {
    float xv = xr[i * 64 + lane];
#pragma unroll
    for (int e2 = 0; e2 < 8; e2++) acc[e2] += xv * smem[e2 * DDIM + i * 64 + lane];
  }
#pragma unroll
  for (int e2 = 0; e2 < 8; e2++) {
    float v = acc[e2];
    v += __shfl_xor(v, 32); v += __shfl_xor(v, 16); v += __shfl_xor(v, 8);
    v += __shfl_xor(v, 4);  v += __shfl_xor(v, 2);  v += __shfl_xor(v, 1);
    acc[e2] = v;
  }
  if (lane == 0) {
    float m0 = -1e30f; int i0 = 0;
#pragma unroll
    for (int e2 = 0; e2 < 8; e2++) if (acc[e2] > m0) { m0 = acc[e2]; i0 = e2; }
    float m1 = -1e30f; int i1 = 0;
#pragma unroll
    for (int e2 = 0; e2 < 8; e2++) if (e2 != i0 && acc[e2] > m1) { m1 = acc[e2]; i1 = e2; }
    float tt = __expf(m1 - m0);
    float w0 = 1.f / (1.f + tt);
    eidx[tok * 2 + 0] = i0; eidx[tok * 2 + 1] = i1;
    wts[tok * 2 + 0] = w0;  wts[tok * 2 + 1] = 1.f - w0;
  }
}

// -------------------- launch 2: scan (hidden) | cvt-W1 e4..7 | cvt-W2 --------------------
__global__ __launch_bounds__(256) void scanCvt_kernel(const int* __restrict__ eidx,
                                                      const float* __restrict__ W1,
                                                      const float* __restrict__ W2,
                                                      int* __restrict__ toklist,
                                                      int* __restrict__ counts,
                                                      int* __restrict__ inv,
                                                      _Float16* __restrict__ w1t,
                                                      _Float16* __restrict__ w2t) {
  __shared__ float smem[2 * 4416];   // cvt tiles (35.3 KB); scan path unused
  int b = blockIdx.x;

  if (b < 16) {                      // ---- scan (one wave; 8-deep load window)
    if (threadIdx.x >= 64) return;
    int z = b;
    int k = z >> 3, e = z & 7;
    int lane = threadIdx.x;
    int pre[8];
#pragma unroll
    for (int c = 0; c < 8; c++) pre[c] = eidx[(c * 64 + lane) * 2 + k];
    int base = 0;
#pragma unroll
    for (int c = 0; c < 64; c++) {
      int my = pre[c & 7];
      if (c < 56) pre[c & 7] = eidx[((c + 8) * 64 + lane) * 2 + k];
      int n = c * 64 + lane;
      bool pred = (my == e);
      unsigned long long mask = __ballot(pred);
      if (pred) {
        int pos = base + __popcll(mask & ((1ull << lane) - 1ull));
        if (pos < CAP) {
          toklist[z * CAPP + pos] = n;
          inv[n * 2 + k] = z * CAPP + pos;
        } else {
          inv[n * 2 + k] = -1;       // capacity-dropped
        }
      }
      base += __popcll(mask);
    }
    if (lane == 0) counts[z] = (base < CAP) ? base : CAP;
    return;
  }

  if (b < 1552) {                    // ---- cvt W1, experts 4..7 (b2 in [1536,3072))
    cvt_w1_block(W1, w1t, 1536 + (b - 16), smem);
    return;
  }

  // ---- cvt W2: 2048x768 per expert (1536 blocks)
  int b2 = b - 1552;                 // 0..1535
  int e = b2 / 192, rem = b2 % 192;
  int cx = rem % 32, cy = rem / 32;  // 32 r-tiles x 6 col2-tiles
  cvt2_tile(W2, w2t, 2048, 768, e, cx * 64, cy * 128, smem);
}

// -------------------- GEMM1 + fused SwiGLU (pure, 1280 blocks) --------------------
__global__ __launch_bounds__(256, 2) void gemm1_kernel(const _Float16* __restrict__ xh,
                                                       const _Float16* __restrict__ w1t,
                                                       const int* __restrict__ toklist,
                                                       const int* __restrict__ counts,
                                                       _Float16* __restrict__ act) {
  __shared__ char smem[49664];   // As 16K | Bs 32K | toks 512

  _Float16* As = (_Float16*)smem;             // 128*64
  _Float16* Bs = (_Float16*)(smem + 16384);   // 256*64
  int* toks = (int*)(smem + 49152);           // 128

  int i = blockIdx.x;
  int xcd = i & 7, j = i >> 3;       // 1280 blocks, 160/xcd
  int m = j % 5, ii = j / 5;
  int k = ii & 1, n = ii >> 1;
  int e = xcd, z = k * 8 + e;
  int count = counts[z];
  int m0 = m * 128;
  if (m0 >= count) return;
  int n0 = n * 128;

  int t = threadIdx.x;
  if (t < 128) {
    int r = m0 + t;
    toks[t] = (r < count) ? toklist[z * CAPP + r] : N_TOK;   // pad -> zero row
  }
  __syncthreads();

  int lane = t & 63, w = t >> 6;
  int l8 = lane >> 3, u8 = lane & 7;

  const _Float16* ag[4]; _Float16* al[4];
#pragma unroll
  for (int s = 0; s < 4; s++) {
    int row = w * 32 + s * 8 + l8;
    ag[s] = xh + (long)toks[row] * DDIM + ((u8 ^ (row & 7)) * 8);
    al[s] = As + row * 64 + u8 * 8;
  }
  const _Float16* bg[8]; _Float16* bl[8];
#pragma unroll
  for (int s = 0; s < 8; s++) {
    int rb = w * 64 + s * 8 + l8;
    int gr = (rb < 128) ? (n0 + rb) : (2048 + n0 + (rb - 128));
    bg[s] = w1t + ((long)e * 4096 + gr) * DDIM + ((u8 ^ (rb & 7)) * 8);
    bl[s] = Bs + rb * 64 + u8 * 8;
  }

  int q = lane >> 4, m16 = lane & 15;
  int wm = w & 1, wn = w >> 1;

  f4 zero4 = {0.f, 0.f, 0.f, 0.f};
  f4 acc[4][4][2];
#pragma unroll
  for (int rt = 0; rt < 4; rt++)
#pragma unroll
    for (int ct = 0; ct < 4; ct++) { acc[rt][ct][0] = zero4; acc[rt][ct][1] = zero4; }

  for (int kk = 0; kk < DDIM; kk += 64) {
    __syncthreads();
#pragma unroll
    for (int s = 0; s < 4; s++) { gld16(ag[s], al[s]); ag[s] += 64; }
#pragma unroll
    for (int s = 0; s < 8; s++) { gld16(bg[s], bl[s]); bg[s] += 64; }
    __syncthreads();

#pragma unroll
    for (int c = 0; c < 2; c++) {
      half8 af[4], bf[4][2];
#pragma unroll
      for (int rt = 0; rt < 4; rt++) {
        int row = wm * 64 + rt * 16 + m16;
        af[rt] = *(const half8*)(As + row * 64 + (((c * 4 + q) ^ (row & 7)) * 8));
      }
#pragma unroll
      for (int ct = 0; ct < 4; ct++) {
        int cb = wn * 64 + ct * 16 + m16;
        int ph = ((c * 4 + q) ^ (cb & 7)) * 8;    // (cb+128)&7 == cb&7
        bf[ct][0] = *(const half8*)(Bs + cb * 64 + ph);
        bf[ct][1] = *(const half8*)(Bs + (128 + cb) * 64 + ph);
      }
#pragma unroll
      for (int rt = 0; rt < 4; rt++)
#pragma unroll
        for (int ct = 0; ct < 4; ct++) {
          acc[rt][ct][0] = __builtin_amdgcn_mfma_f32_16x16x32_f16(af[rt], bf[ct][0], acc[rt][ct][0], 0, 0, 0);
          acc[rt][ct][1] = __builtin_amdgcn_mfma_f32_16x16x32_f16(af[rt], bf[ct][1], acc[rt][ct][1], 0, 0, 0);
        }
    }
  }

  long ab = (long)z * CAPP * HDIM;
#pragma unroll
  for (int rt = 0; rt < 4; rt++)
#pragma unroll
    for (int ct = 0; ct < 4; ct++)
#pragma unroll
      for (int r = 0; r < 4; r++) {
        int row = m0 + wm * 64 + rt * 16 + q * 4 + r;   // C/D: row = quad*4+reg
        int col = n0 + wn * 64 + ct * 16 + m16;         //      col = lane&15
        float h1 = acc[rt][ct][0][r], h2 = acc[rt][ct][1][r];
        float s = h2 / (1.f + __expf(-h2));
        act[ab + (long)row * HDIM + col] = (_Float16)(h1 * s);
      }
}

// -------------------- GEMM2: plain fp32 stores into ybuf (no atomics) --------------------
__global__ __launch_bounds__(256, 3) void gemm2_kernel(const _Float16* __restrict__ act,
                                                       const _Float16* __restrict__ w2t,
                                                       const int* __restrict__ counts,
                                                       float* __restrict__ ybuf) {
  int i = blockIdx.x;
  int xcd = i & 7, j = i >> 3;       // 480 blocks, 60/xcd
  int m = j % 5, t2 = j / 5;         // t2<12: k=t2&1, n=t2>>1 (0..5)
  int k = t2 & 1, n = t2 >> 1;
  int e = xcd, z = k * 8 + e;
  int count = counts[z];
  int m0 = m * 128;
  if (m0 >= count) return;
  int n0 = n * 128;

  __shared__ _Float16 As[128 * 64];   // 16 KB
  __shared__ _Float16 Bs[128 * 64];   // 16 KB

  int t = threadIdx.x;
  int lane = t & 63, w = t >> 6;
  int l8 = lane >> 3, u8 = lane & 7;

  const _Float16* ag[4]; _Float16* al[4];
#pragma unroll
  for (int s = 0; s < 4; s++) {
    int row = w * 32 + s * 8 + l8;
    ag[s] = act + ((long)z * CAPP + m0 + row) * HDIM + ((u8 ^ (row & 7)) * 8);
    al[s] = As + row * 64 + u8 * 8;
  }
  const _Float16* bg[4]; _Float16* bl[4];
#pragma unroll
  for (int s = 0; s < 4; s++) {
    int rb = w * 32 + s * 8 + l8;
    bg[s] = w2t + ((long)e * DDIM + n0 + rb) * HDIM + ((u8 ^ (rb & 7)) * 8);
    bl[s] = Bs + rb * 64 + u8 * 8;
  }

  int q = lane >> 4, m16 = lane & 15;
  int wm = w & 1, wn = w >> 1;

  f4 zero4 = {0.f, 0.f, 0.f, 0.f};
  f4 acc[4][4];
#pragma unroll
  for (int rt = 0; rt < 4; rt++)
#pragma unroll
    for (int ct = 0; ct < 4; ct++) acc[rt][ct] = zero4;

  for (int kk = 0; kk < HDIM; kk += 64) {
    __syncthreads();
#pragma unroll
    for (int s = 0; s < 4; s++) { gld16(ag[s], al[s]); ag[s] += 64; }
#pragma unroll
    for (int s = 0; s < 4; s++) { gld16(bg[s], bl[s]); bg[s] += 64; }
    __syncthreads();

#pragma unroll
    for (int c = 0; c < 2; c++) {
      half8 af[4], bf[4];
#pragma unroll
      for (int rt = 0; rt < 4; rt++) {
        int row = wm * 64 + rt * 16 + m16;
        af[rt] = *(const half8*)(As + row * 64 + (((c * 4 + q) ^ (row & 7)) * 8));
      }
#pragma unroll
      for (int ct = 0; ct < 4; ct++) {
        int cb = wn * 64 + ct * 16 + m16;
        bf[ct] = *(const half8*)(Bs + cb * 64 + (((c * 4 + q) ^ (cb & 7)) * 8));
      }
#pragma unroll
      for (int rt = 0; rt < 4; rt++)
#pragma unroll
        for (int ct = 0; ct < 4; ct++)
          acc[rt][ct] = __builtin_amdgcn_mfma_f32_16x16x32_f16(af[rt], bf[ct], acc[rt][ct], 0, 0, 0);
    }
  }

  // plain stores: ybuf[slot][col] = y (padded slots written, never gathered)
#pragma unroll
  for (int rt = 0; rt < 4; rt++)
#pragma unroll
    for (int ct = 0; ct < 4; ct++)
#pragma unroll
      for (int r = 0; r < 4; r++) {
        int lr = wm * 64 + rt * 16 + q * 4 + r;
        int col = n0 + wn * 64 + ct * 16 + m16;
        ybuf[((long)z * CAPP + m0 + lr) * DDIM + col] = acc[rt][ct][r];
      }
}

// -------------------- gather: out[tok] = sum_k w_k * ybuf[slot_k] --------------------
__global__ __launch_bounds__(256) void gather_kernel(const float* __restrict__ ybuf,
                                                     const int* __restrict__ inv,
                                                     const float* __restrict__ wts,
                                                     float* __restrict__ out) {
  int t = threadIdx.x;
  int w = t >> 6, lane = t & 63;
  int tok = blockIdx.x * 4 + w;
  int s0 = inv[tok * 2 + 0], s1 = inv[tok * 2 + 1];
  float w0 = wts[tok * 2 + 0], w1 = wts[tok * 2 + 1];
  float acc[12];
#pragma unroll
  for (int j = 0; j < 12; j++) acc[j] = 0.f;
  int b = lane * 12;
  if (s0 >= 0) {
    const float* y = ybuf + (long)s0 * DDIM + b;
#pragma unroll
    for (int v = 0; v < 3; v++) {
      f4 qv = *(const f4*)(y + v * 4);
#pragma unroll
      for (int j = 0; j < 4; j++) acc[v * 4 + j] += w0 * qv[j];
    }
  }
  if (s1 >= 0) {
    const float* y = ybuf + (long)s1 * DDIM + b;
#pragma unroll
    for (int v = 0; v < 3; v++) {
      f4 qv = *(const f4*)(y + v * 4);
#pragma unroll
      for (int j = 0; j < 4; j++) acc[v * 4 + j] += w1 * qv[j];
    }
  }
  float* o = out + (long)tok * DDIM + b;
#pragma unroll
  for (int v = 0; v < 3; v++) {
    f4 qv;
#pragma unroll
    for (int j = 0; j < 4; j++) qv[j] = acc[v * 4 + j];
    *(f4*)(o + v * 4) = qv;
  }
}

// -------------------- launch --------------------

extern "C" void kernel_launch(void* const* d_in, const int* in_sizes, int n_in,
                              void* d_out, int out_size, void* d_ws, size_t ws_size,
                              hipStream_t stream) {
  const float* x  = (const float*)d_in[0];
  const float* Wg = (const float*)d_in[1];
  const float* W1 = (const float*)d_in[2];
  const float* W2 = (const float*)d_in[3];
  float* out = (float*)d_out;
  char* ws = (char*)d_ws;

  _Float16* xh   = (_Float16*)(ws + XH_OFF);
  _Float16* w1t  = (_Float16*)(ws + W1T_OFF);
  float*    ybuf = (float*)(ws + YB_OFF);
  _Float16* w2t  = (_Float16*)(ws + W2T_OFF);
  _Float16* actb = (_Float16*)(ws + ACT_OFF);
  int* eidx      = (int*)(ws + EIDX_OFF);
  float* wts     = (float*)(ws + WTS_OFF);
  int* toklist   = (int*)(ws + TOKL_OFF);
  int* counts    = (int*)(ws + CNT_OFF);
  int* inv       = (int*)(ws + INV_OFF);

  routerCvt_kernel<<<2561, 256, 0, stream>>>(x, Wg, W1, xh, w1t, eidx, wts);
  scanCvt_kernel<<<3088, 256, 0, stream>>>(eidx, W1, W2, toklist, counts, inv, w1t, w2t);
  gemm1_kernel<<<1280, 256, 0, stream>>>(xh, w1t, toklist, counts, actb);
  gemm2_kernel<<<480, 256, 0, stream>>>(actb, w2t, counts, ybuf);
  gather_kernel<<<1024, 256, 0, stream>>>(ybuf, inv, wts, out);
}

// Round 14
// 313.253 us; speedup vs baseline: 1.0233x; 1.0233x over previous
//
#include <hip/hip_runtime.h>

// GatedMoE on MI355X (gfx950), fp16 MFMA path, round 18.
// vs r17 (320.6): keep r17's W1-split across the two prep launches
// (balanced BW: L1 = router + cvt-W1[e0..3], L2 = scan(hidden) +
// cvt-W1[e4..7]) but RESTORE r16's gemm1+cvt-W2-tail (2816 blocks).
// r17 proved the tail absorbs W2 conversion for ~12us (rides gemm1's
// drain) while a serial prep launch pays full BW price (~20-28us).
// gemm2/gather byte-identical to r12.

typedef _Float16 half8 __attribute__((ext_vector_type(8)));
typedef _Float16 half4t __attribute__((ext_vector_type(4)));
typedef float f4 __attribute__((ext_vector_type(4)));

#define N_TOK 4096
#define DDIM  768
#define HDIM  2048
#define NEXP  8
#define CAP   614   // int(1.2 * 4096 / 8)
#define CAPP  640

// ---- workspace layout (bytes) ----
#define XH_OFF    0L           // (4097*768) fp16
#define W1T_OFF   6292992L     // [8][4096][768] fp16 (dead after gemm1)
#define YB_OFF    6292992L     // [16][640][768] fp32 ybuf (gemm2->gather), aliases w1t
#define W2T_OFF   56624640L    // [8][768][2048] fp16
#define ACT_OFF   81790464L    // [16][640][2048] fp16
#define EIDX_OFF  123733504L   // [4096][2] int
#define WTS_OFF   123766272L   // [4096][2] float
#define TOKL_OFF  123799040L   // [16][640] int
#define CNT_OFF   123840000L   // [16] int
#define INV_OFF   123840256L   // [4096][2] int (tok,k) -> z*CAPP+slot | -1

__device__ __forceinline__ void gld16(const void* g, void* l) {
  __builtin_amdgcn_global_load_lds(
      (const __attribute__((address_space(1))) unsigned int*)g,
      (__attribute__((address_space(3))) unsigned int*)l, 16, 0, 0);
}

// -------------------- wide transpose+convert: 64 rows x 128 cols --------------------
__device__ __forceinline__ void cvt2_tile(const float* __restrict__ src,
                                          _Float16* __restrict__ dst,
                                          int R, int C, int e, int r0, int c0,
                                          float* __restrict__ tile) {
  long sb = (long)e * R * C;
  int t = threadIdx.x;
  int rrow = t >> 4, c4 = (t & 15) * 4;
#pragma unroll
  for (int h = 0; h < 2; h++)
#pragma unroll
    for (int i = 0; i < 4; i++) {
      int row = i * 16 + rrow;
      f4 v = *(const f4*)(src + sb + (long)(r0 + row) * C + c0 + h * 64 + c4);
      *(f4*)(&tile[h * 4416 + row * 69 + c4]) = v;
    }
  __syncthreads();
#pragma unroll
  for (int h = 0; h < 2; h++)
#pragma unroll
    for (int s = 0; s < 2; s++) {
      int idx = t + s * 256;
      int c = idx >> 3, ch = idx & 7;
      half8 hv;
#pragma unroll
      for (int j = 0; j < 8; j++) hv[j] = (_Float16)tile[h * 4416 + (ch * 8 + j) * 69 + c];
      *(half8*)(dst + sb + (long)(c0 + h * 64 + c) * R + r0 + ch * 8) = hv;
    }
}

// W1 cvt block index b2 in [0,3072): e = b2/384, 12 r-tiles x 32 col2-tiles
__device__ __forceinline__ void cvt_w1_block(const float* __restrict__ W1,
                                             _Float16* __restrict__ w1t,
                                             int b2, float* __restrict__ smem) {
  int e = b2 / 384, rem = b2 % 384;
  int cx = rem % 12, cy = rem / 12;
  cvt2_tile(W1, w1t, 768, 4096, e, cx * 64, cy * 128, smem);
}

// -------------------- launch 1: router (+x->fp16) | cvt-W1 experts 0..3 --------------------
__global__ __launch_bounds__(256) void routerCvt_kernel(const float* __restrict__ x,
                                                        const float* __restrict__ Wg,
                                                        const float* __restrict__ W1,
                                                        _Float16* __restrict__ xh,
                                                        _Float16* __restrict__ w1t,
                                                        int* __restrict__ eidx,
                                                        float* __restrict__ wts) {
  __shared__ float smem[2 * 4416];   // 35.3 KB: cvt tiles; router uses 24 KB as wgT
  int b = blockIdx.x;

  if (b >= 1025) {                   // ---- cvt W1, experts 0..3 (b2 in [0,1536))
    cvt_w1_block(W1, w1t, b - 1025, smem);
    return;
  }

  // ---- router (block-uniform path)
  int t = threadIdx.x;
  for (int i = t; i < DDIM * NEXP; i += 256) smem[(i & 7) * DDIM + (i >> 3)] = Wg[i];
  __syncthreads();
  int w = t >> 6, lane = t & 63;
  int tok = b * 4 + w;
  if (tok > N_TOK) return;
  if (tok == N_TOK) {                // zero pad row
    half4t zz; zz[0] = zz[1] = zz[2] = zz[3] = (_Float16)0.f;
#pragma unroll
    for (int j = 0; j < 3; j++) *(half4t*)(xh + (long)N_TOK * DDIM + (lane + j * 64) * 4) = zz;
    return;
  }
  const float* xr = x + (long)tok * DDIM;
#pragma unroll
  for (int j = 0; j < 3; j++) {
    f4 v = *(const f4*)(xr + (lane + j * 64) * 4);
    half4t hv;
    hv[0] = (_Float16)v[0]; hv[1] = (_Float16)v[1];
    hv[2] = (_Float16)v[2]; hv[3] = (_Float16)v[3];
    *(half4t*)(xh + (long)tok * DDIM + (lane + j * 64) * 4) = hv;
  }
  float acc[8] = {0.f, 0.f, 0.f, 0.f, 0.f, 0.f, 0.f, 0.f};
#pragma unroll
  for (int i = 0; i < 12; i++) {
    float xv = xr[i * 64 + lane];
#pragma unroll
    for (int e2 = 0; e2 < 8; e2++) acc[e2] += xv * smem[e2 * DDIM + i * 64 + lane];
  }
#pragma unroll
  for (int e2 = 0; e2 < 8; e2++) {
    float v = acc[e2];
    v += __shfl_xor(v, 32); v += __shfl_xor(v, 16); v += __shfl_xor(v, 8);
    v += __shfl_xor(v, 4);  v += __shfl_xor(v, 2);  v += __shfl_xor(v, 1);
    acc[e2] = v;
  }
  if (lane == 0) {
    float m0 = -1e30f; int i0 = 0;
#pragma unroll
    for (int e2 = 0; e2 < 8; e2++) if (acc[e2] > m0) { m0 = acc[e2]; i0 = e2; }
    float m1 = -1e30f; int i1 = 0;
#pragma unroll
    for (int e2 = 0; e2 < 8; e2++) if (e2 != i0 && acc[e2] > m1) { m1 = acc[e2]; i1 = e2; }
    float tt = __expf(m1 - m0);
    float w0 = 1.f / (1.f + tt);
    eidx[tok * 2 + 0] = i0; eidx[tok * 2 + 1] = i1;
    wts[tok * 2 + 0] = w0;  wts[tok * 2 + 1] = 1.f - w0;
  }
}

// -------------------- launch 2: scan (hidden) | cvt-W1 experts 4..7 --------------------
__global__ __launch_bounds__(256) void scanCvt_kernel(const int* __restrict__ eidx,
                                                      const float* __restrict__ W1,
                                                      int* __restrict__ toklist,
                                                      int* __restrict__ counts,
                                                      int* __restrict__ inv,
                                                      _Float16* __restrict__ w1t) {
  __shared__ float smem[2 * 4416];   // cvt tiles (35.3 KB); scan path unused
  int b = blockIdx.x;

  if (b < 16) {                      // ---- scan (one wave; 8-deep load window)
    if (threadIdx.x >= 64) return;
    int z = b;
    int k = z >> 3, e = z & 7;
    int lane = threadIdx.x;
    int pre[8];
#pragma unroll
    for (int c = 0; c < 8; c++) pre[c] = eidx[(c * 64 + lane) * 2 + k];
    int base = 0;
#pragma unroll
    for (int c = 0; c < 64; c++) {
      int my = pre[c & 7];
      if (c < 56) pre[c & 7] = eidx[((c + 8) * 64 + lane) * 2 + k];
      int n = c * 64 + lane;
      bool pred = (my == e);
      unsigned long long mask = __ballot(pred);
      if (pred) {
        int pos = base + __popcll(mask & ((1ull << lane) - 1ull));
        if (pos < CAP) {
          toklist[z * CAPP + pos] = n;
          inv[n * 2 + k] = z * CAPP + pos;
        } else {
          inv[n * 2 + k] = -1;       // capacity-dropped
        }
      }
      base += __popcll(mask);
    }
    if (lane == 0) counts[z] = (base < CAP) ? base : CAP;
    return;
  }

  // ---- cvt W1, experts 4..7 (b2 in [1536,3072))
  cvt_w1_block(W1, w1t, 1536 + (b - 16), smem);
}

// -------------------- GEMM1 + fused SwiGLU | appended cvt_tr(W2) --------------------
__global__ __launch_bounds__(256, 2) void gemm1_kernel(const _Float16* __restrict__ xh,
                                                       const _Float16* __restrict__ w1t,
                                                       const float* __restrict__ W2,
                                                       _Float16* __restrict__ w2t,
                                                       const int* __restrict__ toklist,
                                                       const int* __restrict__ counts,
                                                       _Float16* __restrict__ act) {
  __shared__ char smem[49664];   // gemm1: As 16K | Bs 32K | toks 512. cvt: 35.3K

  int i = blockIdx.x;
  if (i >= 1280) {                   // ---- cvt W2: 2048x768 per expert (tail)
    int b2 = i - 1280;               // 0..1535
    int e = b2 / 192, rem = b2 % 192;
    int cx = rem % 32, cy = rem / 32;      // 32 r-tiles x 6 col2-tiles
    cvt2_tile(W2, w2t, 2048, 768, e, cx * 64, cy * 128, (float*)smem);
    return;
  }

  _Float16* As = (_Float16*)smem;             // 128*64
  _Float16* Bs = (_Float16*)(smem + 16384);   // 256*64
  int* toks = (int*)(smem + 49152);           // 128

  int xcd = i & 7, j = i >> 3;       // 1280 blocks, 160/xcd
  int m = j % 5, ii = j / 5;
  int k = ii & 1, n = ii >> 1;
  int e = xcd, z = k * 8 + e;
  int count = counts[z];
  int m0 = m * 128;
  if (m0 >= count) return;
  int n0 = n * 128;

  int t = threadIdx.x;
  if (t < 128) {
    int r = m0 + t;
    toks[t] = (r < count) ? toklist[z * CAPP + r] : N_TOK;   // pad -> zero row
  }
  __syncthreads();

  int lane = t & 63, w = t >> 6;
  int l8 = lane >> 3, u8 = lane & 7;

  const _Float16* ag[4]; _Float16* al[4];
#pragma unroll
  for (int s = 0; s < 4; s++) {
    int row = w * 32 + s * 8 + l8;
    ag[s] = xh + (long)toks[row] * DDIM + ((u8 ^ (row & 7)) * 8);
    al[s] = As + row * 64 + u8 * 8;
  }
  const _Float16* bg[8]; _Float16* bl[8];
#pragma unroll
  for (int s = 0; s < 8; s++) {
    int rb = w * 64 + s * 8 + l8;
    int gr = (rb < 128) ? (n0 + rb) : (2048 + n0 + (rb - 128));
    bg[s] = w1t + ((long)e * 4096 + gr) * DDIM + ((u8 ^ (rb & 7)) * 8);
    bl[s] = Bs + rb * 64 + u8 * 8;
  }

  int q = lane >> 4, m16 = lane & 15;
  int wm = w & 1, wn = w >> 1;

  f4 zero4 = {0.f, 0.f, 0.f, 0.f};
  f4 acc[4][4][2];
#pragma unroll
  for (int rt = 0; rt < 4; rt++)
#pragma unroll
    for (int ct = 0; ct < 4; ct++) { acc[rt][ct][0] = zero4; acc[rt][ct][1] = zero4; }

  for (int kk = 0; kk < DDIM; kk += 64) {
    __syncthreads();
#pragma unroll
    for (int s = 0; s < 4; s++) { gld16(ag[s], al[s]); ag[s] += 64; }
#pragma unroll
    for (int s = 0; s < 8; s++) { gld16(bg[s], bl[s]); bg[s] += 64; }
    __syncthreads();

#pragma unroll
    for (int c = 0; c < 2; c++) {
      half8 af[4], bf[4][2];
#pragma unroll
      for (int rt = 0; rt < 4; rt++) {
        int row = wm * 64 + rt * 16 + m16;
        af[rt] = *(const half8*)(As + row * 64 + (((c * 4 + q) ^ (row & 7)) * 8));
      }
#pragma unroll
      for (int ct = 0; ct < 4; ct++) {
        int cb = wn * 64 + ct * 16 + m16;
        int ph = ((c * 4 + q) ^ (cb & 7)) * 8;    // (cb+128)&7 == cb&7
        bf[ct][0] = *(const half8*)(Bs + cb * 64 + ph);
        bf[ct][1] = *(const half8*)(Bs + (128 + cb) * 64 + ph);
      }
#pragma unroll
      for (int rt = 0; rt < 4; rt++)
#pragma unroll
        for (int ct = 0; ct < 4; ct++) {
          acc[rt][ct][0] = __builtin_amdgcn_mfma_f32_16x16x32_f16(af[rt], bf[ct][0], acc[rt][ct][0], 0, 0, 0);
          acc[rt][ct][1] = __builtin_amdgcn_mfma_f32_16x16x32_f16(af[rt], bf[ct][1], acc[rt][ct][1], 0, 0, 0);
        }
    }
  }

  long ab = (long)z * CAPP * HDIM;
#pragma unroll
  for (int rt = 0; rt < 4; rt++)
#pragma unroll
    for (int ct = 0; ct < 4; ct++)
#pragma unroll
      for (int r = 0; r < 4; r++) {
        int row = m0 + wm * 64 + rt * 16 + q * 4 + r;   // C/D: row = quad*4+reg
        int col = n0 + wn * 64 + ct * 16 + m16;         //      col = lane&15
        float h1 = acc[rt][ct][0][r], h2 = acc[rt][ct][1][r];
        float s = h2 / (1.f + __expf(-h2));
        act[ab + (long)row * HDIM + col] = (_Float16)(h1 * s);
      }
}

// -------------------- GEMM2: plain fp32 stores into ybuf (no atomics) --------------------
__global__ __launch_bounds__(256, 3) void gemm2_kernel(const _Float16* __restrict__ act,
                                                       const _Float16* __restrict__ w2t,
                                                       const int* __restrict__ counts,
                                                       float* __restrict__ ybuf) {
  int i = blockIdx.x;
  int xcd = i & 7, j = i >> 3;       // 480 blocks, 60/xcd
  int m = j % 5, t2 = j / 5;         // t2<12: k=t2&1, n=t2>>1 (0..5)
  int k = t2 & 1, n = t2 >> 1;
  int e = xcd, z = k * 8 + e;
  int count = counts[z];
  int m0 = m * 128;
  if (m0 >= count) return;
  int n0 = n * 128;

  __shared__ _Float16 As[128 * 64];   // 16 KB
  __shared__ _Float16 Bs[128 * 64];   // 16 KB

  int t = threadIdx.x;
  int lane = t & 63, w = t >> 6;
  int l8 = lane >> 3, u8 = lane & 7;

  const _Float16* ag[4]; _Float16* al[4];
#pragma unroll
  for (int s = 0; s < 4; s++) {
    int row = w * 32 + s * 8 + l8;
    ag[s] = act + ((long)z * CAPP + m0 + row) * HDIM + ((u8 ^ (row & 7)) * 8);
    al[s] = As + row * 64 + u8 * 8;
  }
  const _Float16* bg[4]; _Float16* bl[4];
#pragma unroll
  for (int s = 0; s < 4; s++) {
    int rb = w * 32 + s * 8 + l8;
    bg[s] = w2t + ((long)e * DDIM + n0 + rb) * HDIM + ((u8 ^ (rb & 7)) * 8);
    bl[s] = Bs + rb * 64 + u8 * 8;
  }

  int q = lane >> 4, m16 = lane & 15;
  int wm = w & 1, wn = w >> 1;

  f4 zero4 = {0.f, 0.f, 0.f, 0.f};
  f4 acc[4][4];
#pragma unroll
  for (int rt = 0; rt < 4; rt++)
#pragma unroll
    for (int ct = 0; ct < 4; ct++) acc[rt][ct] = zero4;

  for (int kk = 0; kk < HDIM; kk += 64) {
    __syncthreads();
#pragma unroll
    for (int s = 0; s < 4; s++) { gld16(ag[s], al[s]); ag[s] += 64; }
#pragma unroll
    for (int s = 0; s < 4; s++) { gld16(bg[s], bl[s]); bg[s] += 64; }
    __syncthreads();

#pragma unroll
    for (int c = 0; c < 2; c++) {
      half8 af[4], bf[4];
#pragma unroll
      for (int rt = 0; rt < 4; rt++) {
        int row = wm * 64 + rt * 16 + m16;
        af[rt] = *(const half8*)(As + row * 64 + (((c * 4 + q) ^ (row & 7)) * 8));
      }
#pragma unroll
      for (int ct = 0; ct < 4; ct++) {
        int cb = wn * 64 + ct * 16 + m16;
        bf[ct] = *(const half8*)(Bs + cb * 64 + (((c * 4 + q) ^ (cb & 7)) * 8));
      }
#pragma unroll
      for (int rt = 0; rt < 4; rt++)
#pragma unroll
        for (int ct = 0; ct < 4; ct++)
          acc[rt][ct] = __builtin_amdgcn_mfma_f32_16x16x32_f16(af[rt], bf[ct], acc[rt][ct], 0, 0, 0);
    }
  }

  // plain stores: ybuf[slot][col] = y (padded slots written, never gathered)
#pragma unroll
  for (int rt = 0; rt < 4; rt++)
#pragma unroll
    for (int ct = 0; ct < 4; ct++)
#pragma unroll
      for (int r = 0; r < 4; r++) {
        int lr = wm * 64 + rt * 16 + q * 4 + r;
        int col = n0 + wn * 64 + ct * 16 + m16;
        ybuf[((long)z * CAPP + m0 + lr) * DDIM + col] = acc[rt][ct][r];
      }
}

// -------------------- gather: out[tok] = sum_k w_k * ybuf[slot_k] --------------------
__global__ __launch_bounds__(256) void gather_kernel(const float* __restrict__ ybuf,
                                                     const int* __restrict__ inv,
                                                     const float* __restrict__ wts,
                                                     float* __restrict__ out) {
  int t = threadIdx.x;
  int w = t >> 6, lane = t & 63;
  int tok = blockIdx.x * 4 + w;
  int s0 = inv[tok * 2 + 0], s1 = inv[tok * 2 + 1];
  float w0 = wts[tok * 2 + 0], w1 = wts[tok * 2 + 1];
  float acc[12];
#pragma unroll
  for (int j = 0; j < 12; j++) acc[j] = 0.f;
  int b = lane * 12;
  if (s0 >= 0) {
    const float* y = ybuf + (long)s0 * DDIM + b;
#pragma unroll
    for (int v = 0; v < 3; v++) {
      f4 qv = *(const f4*)(y + v * 4);
#pragma unroll
      for (int j = 0; j < 4; j++) acc[v * 4 + j] += w0 * qv[j];
    }
  }
  if (s1 >= 0) {
    const float* y = ybuf + (long)s1 * DDIM + b;
#pragma unroll
    for (int v = 0; v < 3; v++) {
      f4 qv = *(const f4*)(y + v * 4);
#pragma unroll
      for (int j = 0; j < 4; j++) acc[v * 4 + j] += w1 * qv[j];
    }
  }
  float* o = out + (long)tok * DDIM + b;
#pragma unroll
  for (int v = 0; v < 3; v++) {
    f4 qv;
#pragma unroll
    for (int j = 0; j < 4; j++) qv[j] = acc[v * 4 + j];
    *(f4*)(o + v * 4) = qv;
  }
}

// -------------------- launch --------------------

extern "C" void kernel_launch(void* const* d_in, const int* in_sizes, int n_in,
                              void* d_out, int out_size, void* d_ws, size_t ws_size,
                              hipStream_t stream) {
  const float* x  = (const float*)d_in[0];
  const float* Wg = (const float*)d_in[1];
  const float* W1 = (const float*)d_in[2];
  const float* W2 = (const float*)d_in[3];
  float* out = (float*)d_out;
  char* ws = (char*)d_ws;

  _Float16* xh   = (_Float16*)(ws + XH_OFF);
  _Float16* w1t  = (_Float16*)(ws + W1T_OFF);
  float*    ybuf = (float*)(ws + YB_OFF);
  _Float16* w2t  = (_Float16*)(ws + W2T_OFF);
  _Float16* actb = (_Float16*)(ws + ACT_OFF);
  int* eidx      = (int*)(ws + EIDX_OFF);
  float* wts     = (float*)(ws + WTS_OFF);
  int* toklist   = (int*)(ws + TOKL_OFF);
  int* counts    = (int*)(ws + CNT_OFF);
  int* inv       = (int*)(ws + INV_OFF);

  routerCvt_kernel<<<2561, 256, 0, stream>>>(x, Wg, W1, xh, w1t, eidx, wts);
  scanCvt_kernel<<<1552, 256, 0, stream>>>(eidx, W1, toklist, counts, inv, w1t);
  gemm1_kernel<<<2816, 256, 0, stream>>>(xh, w1t, W2, w2t, toklist, counts, actb);
  gemm2_kernel<<<480, 256, 0, stream>>>(actb, w2t, counts, ybuf);
  gather_kernel<<<1024, 256, 0, stream>>>(ybuf, inv, wts, out);
}

// Round 15
// 312.590 us; speedup vs baseline: 1.0255x; 1.0021x over previous
//
#include <hip/hip_runtime.h>

// GatedMoE on MI355X (gfx950), fp16 MFMA path, round 19.
// vs r18 (313.3, best): cvt rewritten to stage fp16 (convert BEFORE LDS)
// -> LDS per converted byte halves -> 64x256 blocks (16 f4 loads in
// flight/thread) at 34.8 KB still run 4 blocks/CU -> 2x memory-level
// parallelism (262 KB in flight/CU). Row-XOR swizzle (c4^((row&3)<<2))
// keeps transpose reads low-conflict. Numerically identical. Applied to
// prep L1, prep L2, and gemm1's W2 tail. All else byte-identical to r18.

typedef _Float16 half8 __attribute__((ext_vector_type(8)));
typedef _Float16 half4t __attribute__((ext_vector_type(4)));
typedef float f4 __attribute__((ext_vector_type(4)));

#define N_TOK 4096
#define DDIM  768
#define HDIM  2048
#define NEXP  8
#define CAP   614   // int(1.2 * 4096 / 8)
#define CAPP  640

// ---- workspace layout (bytes) ----
#define XH_OFF    0L           // (4097*768) fp16
#define W1T_OFF   6292992L     // [8][4096][768] fp16 (dead after gemm1)
#define YB_OFF    6292992L     // [16][640][768] fp32 ybuf (gemm2->gather), aliases w1t
#define W2T_OFF   56624640L    // [8][768][2048] fp16
#define ACT_OFF   81790464L    // [16][640][2048] fp16
#define EIDX_OFF  123733504L   // [4096][2] int
#define WTS_OFF   123766272L   // [4096][2] float
#define TOKL_OFF  123799040L   // [16][640] int
#define CNT_OFF   123840000L   // [16] int
#define INV_OFF   123840256L   // [4096][2] int (tok,k) -> z*CAPP+slot | -1

#define CVT_PH   68            // fp16 tile stride (halves)
#define CVT_TSZ  4352          // 64*68 halves per sub-tile

__device__ __forceinline__ void gld16(const void* g, void* l) {
  __builtin_amdgcn_global_load_lds(
      (const __attribute__((address_space(1))) unsigned int*)g,
      (__attribute__((address_space(3))) unsigned int*)l, 16, 0, 0);
}

// -------------------- wide transpose+convert: 64 rows x 256 cols, fp16-staged --------------------
// src fp32 [e][R][C] tile at (r0,c0) -> dst fp16 [e][C][R]. 16 f4 loads in
// flight per thread; fp16 LDS staging (34.8 KB) keeps 4 blocks/CU resident.
__device__ __forceinline__ void cvt4_tile(const float* __restrict__ src,
                                          _Float16* __restrict__ dst,
                                          int R, int C, int e, int r0, int c0,
                                          _Float16* __restrict__ t16) {
  long sb = (long)e * R * C;
  int t = threadIdx.x;
  int rr = t >> 4, c4 = (t & 15) * 4;
#pragma unroll
  for (int h = 0; h < 4; h++)
#pragma unroll
    for (int i = 0; i < 4; i++) {
      int row = i * 16 + rr;
      f4 v = *(const f4*)(src + sb + (long)(r0 + row) * C + c0 + h * 64 + c4);
      half4t hv;
      hv[0] = (_Float16)v[0]; hv[1] = (_Float16)v[1];
      hv[2] = (_Float16)v[2]; hv[3] = (_Float16)v[3];
      *(half4t*)(&t16[h * CVT_TSZ + row * CVT_PH + (c4 ^ ((row & 3) << 2))]) = hv;
    }
  __syncthreads();
#pragma unroll
  for (int h = 0; h < 4; h++)
#pragma unroll
    for (int s = 0; s < 2; s++) {
      int idx = t + s * 256;
      int c = idx >> 3, ch = idx & 7;
      int cb = c & ~3, ck = c & 3;
      half8 o;
#pragma unroll
      for (int j = 0; j < 8; j++) {
        int row = ch * 8 + j;
        o[j] = t16[h * CVT_TSZ + row * CVT_PH + ((cb ^ ((row & 3) << 2)) | ck)];
      }
      *(half8*)(dst + sb + (long)(c0 + h * 64 + c) * R + r0 + ch * 8) = o;
    }
}

// W1 wide-block index b2 in [0,1536): e = b2/192, 12 r-tiles x 16 c256-tiles
__device__ __forceinline__ void cvt_w1_block(const float* __restrict__ W1,
                                             _Float16* __restrict__ w1t,
                                             int b2, _Float16* __restrict__ t16) {
  int e = b2 / 192, rem = b2 % 192;
  int cx = rem % 12, cy = rem / 12;
  cvt4_tile(W1, w1t, 768, 4096, e, cx * 64, cy * 256, t16);
}

// -------------------- launch 1: router (+x->fp16) | cvt-W1 experts 0..3 --------------------
__global__ __launch_bounds__(256) void routerCvt_kernel(const float* __restrict__ x,
                                                        const float* __restrict__ Wg,
                                                        const float* __restrict__ W1,
                                                        _Float16* __restrict__ xh,
                                                        _Float16* __restrict__ w1t,
                                                        int* __restrict__ eidx,
                                                        float* __restrict__ wts) {
  __shared__ float smem[NEXP * DDIM];   // 24 KB wgT; cvt reuses as fp16 tiles (17.4K halves <= 24KB... )
  __shared__ _Float16 tpad[4 * CVT_TSZ - NEXP * DDIM > 0 ? 1 : 1];  // (unused)
  __shared__ _Float16 t16s[4 * CVT_TSZ];  // 34.8 KB fp16 tiles for cvt path
  int b = blockIdx.x;

  if (b >= 1025) {                   // ---- cvt W1, experts 0..3 (b2 in [0,768))
    cvt_w1_block(W1, w1t, b - 1025, t16s);
    return;
  }

  // ---- router (block-uniform path)
  int t = threadIdx.x;
  for (int i = t; i < DDIM * NEXP; i += 256) smem[(i & 7) * DDIM + (i >> 3)] = Wg[i];
  __syncthreads();
  int w = t >> 6, lane = t & 63;
  int tok = b * 4 + w;
  if (tok > N_TOK) return;
  if (tok == N_TOK) {                // zero pad row
    half4t zz; zz[0] = zz[1] = zz[2] = zz[3] = (_Float16)0.f;
#pragma unroll
    for (int j = 0; j < 3; j++) *(half4t*)(xh + (long)N_TOK * DDIM + (lane + j * 64) * 4) = zz;
    return;
  }
  const float* xr = x + (long)tok * DDIM;
#pragma unroll
  for (int j = 0; j < 3; j++) {
    f4 v = *(const f4*)(xr + (lane + j * 64) * 4);
    half4t hv;
    hv[0] = (_Float16)v[0]; hv[1] = (_Float16)v[1];
    hv[2] = (_Float16)v[2]; hv[3] = (_Float16)v[3];
    *(half4t*)(xh + (long)tok * DDIM + (lane + j * 64) * 4) = hv;
  }
  float acc[8] = {0.f, 0.f, 0.f, 0.f, 0.f, 0.f, 0.f, 0.f};
#pragma unroll
  for (int i = 0; i < 12; i++) {
    float xv = xr[i * 64 + lane];
#pragma unroll
    for (int e2 = 0; e2 < 8; e2++) acc[e2] += xv * smem[e2 * DDIM + i * 64 + lane];
  }
#pragma unroll
  for (int e2 = 0; e2 < 8; e2++) {
    float v = acc[e2];
    v += __shfl_xor(v, 32); v += __shfl_xor(v, 16); v += __shfl_xor(v, 8);
    v += __shfl_xor(v, 4);  v += __shfl_xor(v, 2);  v += __shfl_xor(v, 1);
    acc[e2] = v;
  }
  if (lane == 0) {
    float m0 = -1e30f; int i0 = 0;
#pragma unroll
    for (int e2 = 0; e2 < 8; e2++) if (acc[e2] > m0) { m0 = acc[e2]; i0 = e2; }
    float m1 = -1e30f; int i1 = 0;
#pragma unroll
    for (int e2 = 0; e2 < 8; e2++) if (e2 != i0 && acc[e2] > m1) { m1 = acc[e2]; i1 = e2; }
    float tt = __expf(m1 - m0);
    float w0 = 1.f / (1.f + tt);
    eidx[tok * 2 + 0] = i0; eidx[tok * 2 + 1] = i1;
    wts[tok * 2 + 0] = w0;  wts[tok * 2 + 1] = 1.f - w0;
  }
}

// -------------------- launch 2: scan (hidden) | cvt-W1 experts 4..7 --------------------
__global__ __launch_bounds__(256) void scanCvt_kernel(const int* __restrict__ eidx,
                                                      const float* __restrict__ W1,
                                                      int* __restrict__ toklist,
                                                      int* __restrict__ counts,
                                                      int* __restrict__ inv,
                                                      _Float16* __restrict__ w1t) {
  __shared__ _Float16 t16s[4 * CVT_TSZ];  // 34.8 KB
  int b = blockIdx.x;

  if (b < 16) {                      // ---- scan (one wave; 8-deep load window)
    if (threadIdx.x >= 64) return;
    int z = b;
    int k = z >> 3, e = z & 7;
    int lane = threadIdx.x;
    int pre[8];
#pragma unroll
    for (int c = 0; c < 8; c++) pre[c] = eidx[(c * 64 + lane) * 2 + k];
    int base = 0;
#pragma unroll
    for (int c = 0; c < 64; c++) {
      int my = pre[c & 7];
      if (c < 56) pre[c & 7] = eidx[((c + 8) * 64 + lane) * 2 + k];
      int n = c * 64 + lane;
      bool pred = (my == e);
      unsigned long long mask = __ballot(pred);
      if (pred) {
        int pos = base + __popcll(mask & ((1ull << lane) - 1ull));
        if (pos < CAP) {
          toklist[z * CAPP + pos] = n;
          inv[n * 2 + k] = z * CAPP + pos;
        } else {
          inv[n * 2 + k] = -1;       // capacity-dropped
        }
      }
      base += __popcll(mask);
    }
    if (lane == 0) counts[z] = (base < CAP) ? base : CAP;
    return;
  }

  // ---- cvt W1, experts 4..7 (b2 in [768,1536))
  cvt_w1_block(W1, w1t, 768 + (b - 16), t16s);
}

// -------------------- GEMM1 + fused SwiGLU | appended cvt_tr(W2) --------------------
__global__ __launch_bounds__(256, 2) void gemm1_kernel(const _Float16* __restrict__ xh,
                                                       const _Float16* __restrict__ w1t,
                                                       const float* __restrict__ W2,
                                                       _Float16* __restrict__ w2t,
                                                       const int* __restrict__ toklist,
                                                       const int* __restrict__ counts,
                                                       _Float16* __restrict__ act) {
  __shared__ char smem[49664];   // gemm1: As 16K | Bs 32K | toks 512. cvt: 34.8K

  int i = blockIdx.x;
  if (i >= 1280) {                   // ---- cvt W2 (tail): 2048x768 per expert
    int b2 = i - 1280;               // 0..767; 32 r-tiles x 3 c256-tiles
    int e = b2 / 96, rem = b2 % 96;
    int cx = rem % 32, cy = rem / 32;
    cvt4_tile(W2, w2t, 2048, 768, e, cx * 64, cy * 256, (_Float16*)smem);
    return;
  }

  _Float16* As = (_Float16*)smem;             // 128*64
  _Float16* Bs = (_Float16*)(smem + 16384);   // 256*64
  int* toks = (int*)(smem + 49152);           // 128

  int xcd = i & 7, j = i >> 3;       // 1280 blocks, 160/xcd
  int m = j % 5, ii = j / 5;
  int k = ii & 1, n = ii >> 1;
  int e = xcd, z = k * 8 + e;
  int count = counts[z];
  int m0 = m * 128;
  if (m0 >= count) return;
  int n0 = n * 128;

  int t = threadIdx.x;
  if (t < 128) {
    int r = m0 + t;
    toks[t] = (r < count) ? toklist[z * CAPP + r] : N_TOK;   // pad -> zero row
  }
  __syncthreads();

  int lane = t & 63, w = t >> 6;
  int l8 = lane >> 3, u8 = lane & 7;

  const _Float16* ag[4]; _Float16* al[4];
#pragma unroll
  for (int s = 0; s < 4; s++) {
    int row = w * 32 + s * 8 + l8;
    ag[s] = xh + (long)toks[row] * DDIM + ((u8 ^ (row & 7)) * 8);
    al[s] = As + row * 64 + u8 * 8;
  }
  const _Float16* bg[8]; _Float16* bl[8];
#pragma unroll
  for (int s = 0; s < 8; s++) {
    int rb = w * 64 + s * 8 + l8;
    int gr = (rb < 128) ? (n0 + rb) : (2048 + n0 + (rb - 128));
    bg[s] = w1t + ((long)e * 4096 + gr) * DDIM + ((u8 ^ (rb & 7)) * 8);
    bl[s] = Bs + rb * 64 + u8 * 8;
  }

  int q = lane >> 4, m16 = lane & 15;
  int wm = w & 1, wn = w >> 1;

  f4 zero4 = {0.f, 0.f, 0.f, 0.f};
  f4 acc[4][4][2];
#pragma unroll
  for (int rt = 0; rt < 4; rt++)
#pragma unroll
    for (int ct = 0; ct < 4; ct++) { acc[rt][ct][0] = zero4; acc[rt][ct][1] = zero4; }

  for (int kk = 0; kk < DDIM; kk += 64) {
    __syncthreads();
#pragma unroll
    for (int s = 0; s < 4; s++) { gld16(ag[s], al[s]); ag[s] += 64; }
#pragma unroll
    for (int s = 0; s < 8; s++) { gld16(bg[s], bl[s]); bg[s] += 64; }
    __syncthreads();

#pragma unroll
    for (int c = 0; c < 2; c++) {
      half8 af[4], bf[4][2];
#pragma unroll
      for (int rt = 0; rt < 4; rt++) {
        int row = wm * 64 + rt * 16 + m16;
        af[rt] = *(const half8*)(As + row * 64 + (((c * 4 + q) ^ (row & 7)) * 8));
      }
#pragma unroll
      for (int ct = 0; ct < 4; ct++) {
        int cb = wn * 64 + ct * 16 + m16;
        int ph = ((c * 4 + q) ^ (cb & 7)) * 8;    // (cb+128)&7 == cb&7
        bf[ct][0] = *(const half8*)(Bs + cb * 64 + ph);
        bf[ct][1] = *(const half8*)(Bs + (128 + cb) * 64 + ph);
      }
#pragma unroll
      for (int rt = 0; rt < 4; rt++)
#pragma unroll
        for (int ct = 0; ct < 4; ct++) {
          acc[rt][ct][0] = __builtin_amdgcn_mfma_f32_16x16x32_f16(af[rt], bf[ct][0], acc[rt][ct][0], 0, 0, 0);
          acc[rt][ct][1] = __builtin_amdgcn_mfma_f32_16x16x32_f16(af[rt], bf[ct][1], acc[rt][ct][1], 0, 0, 0);
        }
    }
  }

  long ab = (long)z * CAPP * HDIM;
#pragma unroll
  for (int rt = 0; rt < 4; rt++)
#pragma unroll
    for (int ct = 0; ct < 4; ct++)
#pragma unroll
      for (int r = 0; r < 4; r++) {
        int row = m0 + wm * 64 + rt * 16 + q * 4 + r;   // C/D: row = quad*4+reg
        int col = n0 + wn * 64 + ct * 16 + m16;         //      col = lane&15
        float h1 = acc[rt][ct][0][r], h2 = acc[rt][ct][1][r];
        float s = h2 / (1.f + __expf(-h2));
        act[ab + (long)row * HDIM + col] = (_Float16)(h1 * s);
      }
}

// -------------------- GEMM2: plain fp32 stores into ybuf (no atomics) --------------------
__global__ __launch_bounds__(256, 3) void gemm2_kernel(const _Float16* __restrict__ act,
                                                       const _Float16* __restrict__ w2t,
                                                       const int* __restrict__ counts,
                                                       float* __restrict__ ybuf) {
  int i = blockIdx.x;
  int xcd = i & 7, j = i >> 3;       // 480 blocks, 60/xcd
  int m = j % 5, t2 = j / 5;         // t2<12: k=t2&1, n=t2>>1 (0..5)
  int k = t2 & 1, n = t2 >> 1;
  int e = xcd, z = k * 8 + e;
  int count = counts[z];
  int m0 = m * 128;
  if (m0 >= count) return;
  int n0 = n * 128;

  __shared__ _Float16 As[128 * 64];   // 16 KB
  __shared__ _Float16 Bs[128 * 64];   // 16 KB

  int t = threadIdx.x;
  int lane = t & 63, w = t >> 6;
  int l8 = lane >> 3, u8 = lane & 7;

  const _Float16* ag[4]; _Float16* al[4];
#pragma unroll
  for (int s = 0; s < 4; s++) {
    int row = w * 32 + s * 8 + l8;
    ag[s] = act + ((long)z * CAPP + m0 + row) * HDIM + ((u8 ^ (row & 7)) * 8);
    al[s] = As + row * 64 + u8 * 8;
  }
  const _Float16* bg[4]; _Float16* bl[4];
#pragma unroll
  for (int s = 0; s < 4; s++) {
    int rb = w * 32 + s * 8 + l8;
    bg[s] = w2t + ((long)e * DDIM + n0 + rb) * HDIM + ((u8 ^ (rb & 7)) * 8);
    bl[s] = Bs + rb * 64 + u8 * 8;
  }

  int q = lane >> 4, m16 = lane & 15;
  int wm = w & 1, wn = w >> 1;

  f4 zero4 = {0.f, 0.f, 0.f, 0.f};
  f4 acc[4][4];
#pragma unroll
  for (int rt = 0; rt < 4; rt++)
#pragma unroll
    for (int ct = 0; ct < 4; ct++) acc[rt][ct] = zero4;

  for (int kk = 0; kk < HDIM; kk += 64) {
    __syncthreads();
#pragma unroll
    for (int s = 0; s < 4; s++) { gld16(ag[s], al[s]); ag[s] += 64; }
#pragma unroll
    for (int s = 0; s < 4; s++) { gld16(bg[s], bl[s]); bg[s] += 64; }
    __syncthreads();

#pragma unroll
    for (int c = 0; c < 2; c++) {
      half8 af[4], bf[4];
#pragma unroll
      for (int rt = 0; rt < 4; rt++) {
        int row = wm * 64 + rt * 16 + m16;
        af[rt] = *(const half8*)(As + row * 64 + (((c * 4 + q) ^ (row & 7)) * 8));
      }
#pragma unroll
      for (int ct = 0; ct < 4; ct++) {
        int cb = wn * 64 + ct * 16 + m16;
        bf[ct] = *(const half8*)(Bs + cb * 64 + (((c * 4 + q) ^ (cb & 7)) * 8));
      }
#pragma unroll
      for (int rt = 0; rt < 4; rt++)
#pragma unroll
        for (int ct = 0; ct < 4; ct++)
          acc[rt][ct] = __builtin_amdgcn_mfma_f32_16x16x32_f16(af[rt], bf[ct], acc[rt][ct], 0, 0, 0);
    }
  }

  // plain stores: ybuf[slot][col] = y (padded slots written, never gathered)
#pragma unroll
  for (int rt = 0; rt < 4; rt++)
#pragma unroll
    for (int ct = 0; ct < 4; ct++)
#pragma unroll
      for (int r = 0; r < 4; r++) {
        int lr = wm * 64 + rt * 16 + q * 4 + r;
        int col = n0 + wn * 64 + ct * 16 + m16;
        ybuf[((long)z * CAPP + m0 + lr) * DDIM + col] = acc[rt][ct][r];
      }
}

// -------------------- gather: out[tok] = sum_k w_k * ybuf[slot_k] --------------------
__global__ __launch_bounds__(256) void gather_kernel(const float* __restrict__ ybuf,
                                                     const int* __restrict__ inv,
                                                     const float* __restrict__ wts,
                                                     float* __restrict__ out) {
  int t = threadIdx.x;
  int w = t >> 6, lane = t & 63;
  int tok = blockIdx.x * 4 + w;
  int s0 = inv[tok * 2 + 0], s1 = inv[tok * 2 + 1];
  float w0 = wts[tok * 2 + 0], w1 = wts[tok * 2 + 1];
  float acc[12];
#pragma unroll
  for (int j = 0; j < 12; j++) acc[j] = 0.f;
  int b = lane * 12;
  if (s0 >= 0) {
    const float* y = ybuf + (long)s0 * DDIM + b;
#pragma unroll
    for (int v = 0; v < 3; v++) {
      f4 qv = *(const f4*)(y + v * 4);
#pragma unroll
      for (int j = 0; j < 4; j++) acc[v * 4 + j] += w0 * qv[j];
    }
  }
  if (s1 >= 0) {
    const float* y = ybuf + (long)s1 * DDIM + b;
#pragma unroll
    for (int v = 0; v < 3; v++) {
      f4 qv = *(const f4*)(y + v * 4);
#pragma unroll
      for (int j = 0; j < 4; j++) acc[v * 4 + j] += w1 * qv[j];
    }
  }
  float* o = out + (long)tok * DDIM + b;
#pragma unroll
  for (int v = 0; v < 3; v++) {
    f4 qv;
#pragma unroll
    for (int j = 0; j < 4; j++) qv[j] = acc[v * 4 + j];
    *(f4*)(o + v * 4) = qv;
  }
}

// -------------------- launch --------------------

extern "C" void kernel_launch(void* const* d_in, const int* in_sizes, int n_in,
                              void* d_out, int out_size, void* d_ws, size_t ws_size,
                              hipStream_t stream) {
  const float* x  = (const float*)d_in[0];
  const float* Wg = (const float*)d_in[1];
  const float* W1 = (const float*)d_in[2];
  const float* W2 = (const float*)d_in[3];
  float* out = (float*)d_out;
  char* ws = (char*)d_ws;

  _Float16* xh   = (_Float16*)(ws + XH_OFF);
  _Float16* w1t  = (_Float16*)(ws + W1T_OFF);
  float*    ybuf = (float*)(ws + YB_OFF);
  _Float16* w2t  = (_Float16*)(ws + W2T_OFF);
  _Float16* actb = (_Float16*)(ws + ACT_OFF);
  int* eidx      = (int*)(ws + EIDX_OFF);
  float* wts     = (float*)(ws + WTS_OFF);
  int* toklist   = (int*)(ws + TOKL_OFF);
  int* counts    = (int*)(ws + CNT_OFF);
  int* inv       = (int*)(ws + INV_OFF);

  routerCvt_kernel<<<1793, 256, 0, stream>>>(x, Wg, W1, xh, w1t, eidx, wts);
  scanCvt_kernel<<<784, 256, 0, stream>>>(eidx, W1, toklist, counts, inv, w1t);
  gemm1_kernel<<<2048, 256, 0, stream>>>(xh, w1t, W2, w2t, toklist, counts, actb);
  gemm2_kernel<<<480, 256, 0, stream>>>(actb, w2t, counts, ybuf);
  gather_kernel<<<1024, 256, 0, stream>>>(ybuf, inv, wts, out);
}